// Round 5
// baseline (422.292 us; speedup 1.0000x reference)
//
#include <hip/hip_runtime.h>

// Output layout per row: [0..11] = x, [12..77] = size-2 combos,
// [78..297] = size-3, [298..792] = size-4 (lexicographic = itertools).
#define NCOMBO 781
#define NCOLS  793
#define NROWS  131072

struct ComboTable { unsigned m[NCOMBO]; };

constexpr ComboTable make_combos() {
    ComboTable t{};
    int k = 0;
    for (int i = 0; i < 12; ++i)
        for (int j = i + 1; j < 12; ++j)
            t.m[k++] = (1u << i) | (1u << j);
    for (int i = 0; i < 12; ++i)
        for (int j = i + 1; j < 12; ++j)
            for (int l = j + 1; l < 12; ++l)
                t.m[k++] = (1u << i) | (1u << j) | (1u << l);
    for (int i = 0; i < 12; ++i)
        for (int j = i + 1; j < 12; ++j)
            for (int l = j + 1; l < 12; ++l)
                for (int p = l + 1; p < 12; ++p)
                    t.m[k++] = (1u << i) | (1u << j) | (1u << l) | (1u << p);
    return t;
}

__constant__ ComboTable g_combos = make_combos();

// Fold semantics: dp(a,b) = (b==1) ? a : ((a==1) ? b : 0).
// 1.0 identity; >=2 non-1 elements -> 0; exactly 1 -> that element.
// With mm = "not equal to 1.0" bitmask of the row:
//   popc(combo & mm) == 0 -> 1.0 ; == 1 -> x[that bit] ; else 0.0.
// If mm == 0xFFF every combo output is 0 -> the memset already wrote it.

__global__ __launch_bounds__(256)
void finish_kernel(const float* __restrict__ x, float* __restrict__ out,
                   int nrows) {
    const int stride = gridDim.x * 256;
    for (int row = blockIdx.x * 256 + threadIdx.x; row < nrows; row += stride) {
        const float4* p = reinterpret_cast<const float4*>(x + (size_t)row * 12);
        float4 a = p[0], b = p[1], c = p[2];
        float v[12] = {a.x, a.y, a.z, a.w, b.x, b.y, b.z, b.w,
                       c.x, c.y, c.z, c.w};
        unsigned m = 0;
        #pragma unroll
        for (int i = 0; i < 12; ++i)
            if (v[i] != 1.0f) m |= (1u << i);

        float* orow = out + (size_t)row * NCOLS;
        // Passthrough columns (memset left them 0). 48 B per row; adjacent
        // lanes hit adjacent rows -> L2 write-combines the 3172 B-stride segs.
        #pragma unroll
        for (int i = 0; i < 12; ++i) orow[i] = v[i];

        // Rare path: the row contains at least one exact 1.0 -> some combo
        // outputs are nonzero. Exec-skipped entirely on typical data.
        if (m != 0xFFFu) {
            for (int k = 0; k < NCOMBO; ++k) {
                const unsigned no = g_combos.m[k] & m;
                const int cnt = __popc(no);
                float r = (cnt == 0) ? 1.0f : 0.0f;
                if (cnt == 1) r = v[__ffs(no) - 1];
                orow[12 + k] = r;
            }
        }
    }
}

extern "C" void kernel_launch(void* const* d_in, const int* in_sizes, int n_in,
                              void* d_out, int out_size, void* d_ws, size_t ws_size,
                              hipStream_t stream) {
    const float* x = (const float*)d_in[0];
    float* out = (float*)d_out;
    const int nrows = in_sizes[0] / 12;   // 131072

    // Bulk: all combo outputs are 0 unless the row contains an exact 1.0.
    // Zero everything at hardware-fill speed, then patch.
    hipMemsetAsync(d_out, 0, (size_t)out_size * sizeof(float), stream);
    finish_kernel<<<512, 256, 0, stream>>>(x, out, nrows);
}